// Round 1
// baseline (46.635 us; speedup 1.0000x reference)
//
#include <hip/hip_runtime.h>

// LSTM_8589935226: B=4194304 independent LSTMs, T=4, I=1, H=2, C=1.
// One thread per batch element; weights are grid-uniform scalars.

__device__ __forceinline__ float fexp2(float x) { return __builtin_amdgcn_exp2f(x); }
__device__ __forceinline__ float frcp(float x)  { return __builtin_amdgcn_rcpf(x); }

// sigmoid(x) = 1 / (1 + 2^(-x*log2(e)))
__device__ __forceinline__ float fsigmoid(float x) {
    return frcp(1.0f + fexp2(x * -1.4426950408889634f));
}
// tanh(x) = 1 - 2 / (e^{2x} + 1), e^{2x} = 2^(x*2*log2(e))
__device__ __forceinline__ float ftanh_fast(float x) {
    float e = fexp2(x * 2.8853900817779268f);
    return 1.0f - 2.0f * frcp(e + 1.0f);
}

__global__ __launch_bounds__(256) void lstm_fused(
    const float4* __restrict__ x,     // [B] float4 = 4 timesteps (I=1)
    const float*  __restrict__ W_ih,  // [8]  (4H x I)
    const float*  __restrict__ W_hh,  // [16] (4H x H), row-major
    const float*  __restrict__ b_ih,  // [8]
    const float*  __restrict__ b_hh,  // [8]
    const float*  __restrict__ W_fc,  // [2]  (C x H)
    const float*  __restrict__ b_fc,  // [1]
    float* __restrict__ out,          // [B]
    int B)
{
    int idx = blockIdx.x * blockDim.x + threadIdx.x;
    if (idx >= B) return;

    // Grid-uniform weights: uniform address -> scalar loads / cached.
    float wi[8], wh0[8], wh1[8], bb[8];
#pragma unroll
    for (int k = 0; k < 8; ++k) {
        wi[k]  = W_ih[k];
        wh0[k] = W_hh[2 * k];
        wh1[k] = W_hh[2 * k + 1];
        bb[k]  = b_ih[k] + b_hh[k];
    }
    const float wf0 = W_fc[0], wf1 = W_fc[1], bf = b_fc[0];

    const float4 xv = x[idx];
    const float xs[4] = {xv.x, xv.y, xv.z, xv.w};

    float h0 = 0.f, h1 = 0.f, c0 = 0.f, c1 = 0.f;
#pragma unroll
    for (int t = 0; t < 4; ++t) {
        const float xt = xs[t];
        float g[8];
#pragma unroll
        for (int k = 0; k < 8; ++k)
            g[k] = fmaf(xt, wi[k], fmaf(h0, wh0[k], fmaf(h1, wh1[k], bb[k])));
        // packed gate order: i(0,1) f(2,3) g(4,5) o(6,7)
        const float i0 = fsigmoid(g[0]),   i1 = fsigmoid(g[1]);
        const float f0 = fsigmoid(g[2]),   f1 = fsigmoid(g[3]);
        const float gg0 = ftanh_fast(g[4]), gg1 = ftanh_fast(g[5]);
        const float o0 = fsigmoid(g[6]),   o1 = fsigmoid(g[7]);
        c0 = fmaf(f0, c0, i0 * gg0);
        c1 = fmaf(f1, c1, i1 * gg1);
        h0 = o0 * ftanh_fast(c0);
        h1 = o1 * ftanh_fast(c1);
    }
    out[idx] = fmaf(h0, wf0, fmaf(h1, wf1, bf));
}

extern "C" void kernel_launch(void* const* d_in, const int* in_sizes, int n_in,
                              void* d_out, int out_size, void* d_ws, size_t ws_size,
                              hipStream_t stream)
{
    const float4* x    = (const float4*)d_in[0];
    const float*  W_ih = (const float*)d_in[1];
    const float*  W_hh = (const float*)d_in[2];
    const float*  b_ih = (const float*)d_in[3];
    const float*  b_hh = (const float*)d_in[4];
    const float*  W_fc = (const float*)d_in[5];
    const float*  b_fc = (const float*)d_in[6];
    float* out = (float*)d_out;

    const int B = in_sizes[0] / 4;  // T*I = 4 floats per batch element
    const int threads = 256;
    const int blocks = (B + threads - 1) / threads;
    lstm_fused<<<blocks, threads, 0, stream>>>(x, W_ih, W_hh, b_ih, b_hh,
                                               W_fc, b_fc, out, B);
}